// Round 1
// baseline (2416.274 us; speedup 1.0000x reference)
//
#include <hip/hip_runtime.h>

#define Bn 20
#define Cn 395
#define Hn 10
#define Tn 8192
#define GIN 800   // 2*C + H
#define NL2E (-1.4426950408889634f)

// ---------------- Phase 1: pre[t,b,g,h] = x.Wx + y_prev.Wy + bias, pre-scaled by -log2e*k_g ----
__global__ __launch_bounds__(256) void pclstm_pre(
    const float* __restrict__ x, const float* __restrict__ y,
    const float* __restrict__ Wf, const float* __restrict__ Wi,
    const float* __restrict__ Wu, const float* __restrict__ Wo,
    const float* __restrict__ bfp, const float* __restrict__ bip,
    const float* __restrict__ bup, const float* __restrict__ bop,
    float* __restrict__ pre)
{
  __shared__ float wl[79 * 80];            // [c_local][80]: 40 Wx(gh) then 40 Wy(gh)
  const int tid = threadIdx.x;
  const int b = blockIdx.y;
  const int t = blockIdx.x * 256 + tid;

  const float* Wg[4] = {Wf, Wi, Wu, Wo};
  const float* bg[4] = {bfp, bip, bup, bop};

  float acc[40];
#pragma unroll
  for (int q = 0; q < 40; ++q) acc[q] = bg[q / 10][q % 10];

  for (int c0 = 0; c0 < Cn; c0 += 79) {    // 5 chunks of 79 = 395
    __syncthreads();
    for (int idx = tid; idx < 79 * 80; idx += 256) {
      int cl = idx / 80;
      int q  = idx - cl * 80;
      int qq = (q < 40) ? q : q - 40;
      int g  = qq / 10;
      int h  = qq - g * 10;
      int col = (q < 40) ? (c0 + cl) : (Cn + Hn + c0 + cl);
      wl[idx] = Wg[g][h * GIN + col];
    }
    __syncthreads();
#pragma unroll 2
    for (int cl = 0; cl < 79; ++cl) {
      int c = c0 + cl;
      float xv = x[(b * Cn + c) * Tn + t];
      float yv = (t > 0) ? y[(b * Cn + c) * Tn + t - 1] : 0.f;
      const float4* wrow = reinterpret_cast<const float4*>(&wl[cl * 80]);
#pragma unroll
      for (int k = 0; k < 10; ++k) {
        float4 wx = wrow[k];
        float4 wy = wrow[k + 10];
        acc[4*k+0] = fmaf(xv, wx.x, acc[4*k+0]);
        acc[4*k+1] = fmaf(xv, wx.y, acc[4*k+1]);
        acc[4*k+2] = fmaf(xv, wx.z, acc[4*k+2]);
        acc[4*k+3] = fmaf(xv, wx.w, acc[4*k+3]);
        acc[4*k+0] = fmaf(yv, wy.x, acc[4*k+0]);
        acc[4*k+1] = fmaf(yv, wy.y, acc[4*k+1]);
        acc[4*k+2] = fmaf(yv, wy.z, acc[4*k+2]);
        acc[4*k+3] = fmaf(yv, wy.w, acc[4*k+3]);
      }
    }
  }
  // store scaled: z' = -log2e * k_g * z  (k=2 for the tanh gate g==2 -> q in [20,30))
  float* dst = pre + ((size_t)b * Tn + t) * 40;
#pragma unroll
  for (int q = 0; q < 40; ++q) {
    float s = (q >= 20 && q < 30) ? 2.f * NL2E : NL2E;
    dst[q] = acc[q] * s;
  }
}

// ---------------- Phase 2: sequential scan, one wave per batch --------------------------------
// lane l = g*10+o (l<40): computes z[g,o]; lanes 0..9 hold c[o],h[o].
// sigmoid(z) = rcp(1+exp2(z'))  with z' pre-scaled; tanh(z) = 2*sigmoid(2z)-1.
__global__ __launch_bounds__(64) void pclstm_scan(
    const float* __restrict__ pre,
    const float* __restrict__ Wf, const float* __restrict__ Wi,
    const float* __restrict__ Wu, const float* __restrict__ Wo,
    const float* __restrict__ b_init,
    float* __restrict__ out)
{
  const int b = blockIdx.x;
  const int l = threadIdx.x;
  const int lc = (l < 40) ? l : 39;
  const int g = lc / 10;
  const int o = lc - g * 10;

  const float* W  = (g == 0) ? Wf : (g == 1) ? Wi : (g == 2) ? Wu : Wo;
  const float sg  = (g == 2) ? 2.f * NL2E : NL2E;   // fold -log2e * k_g into Wh
  const float ag  = (g == 2) ? 2.f : 1.f;           // gate = ag*sig + bgc
  const float bgc = (g == 2) ? -1.f : 0.f;

  float wh[10];
#pragma unroll
  for (int j = 0; j < 10; ++j) wh[j] = W[o * GIN + Cn + j] * sg;

  const float* preb = pre + (size_t)b * Tn * 40 + l;
  float c = (l < 10) ? b_init[l] : 0.f;
  float h = 0.f;
  float hb[10];
#pragma unroll
  for (int j = 0; j < 10; ++j) hb[j] = 0.f;

  float pbuf[8];
#pragma unroll
  for (int k = 0; k < 8; ++k) pbuf[k] = preb[(size_t)k * 40];

  const int a1 = ((l + 10) & 63) << 2;   // bpermute byte addresses (precomputed)
  const int a2 = ((l + 20) & 63) << 2;
  const int a3 = ((l + 30) & 63) << 2;

  float* outb = out + (size_t)b * Hn * Tn;
  float* cTp  = out + (size_t)Bn * Hn * Tn + b * Hn;

#pragma unroll 8
  for (int t = 0; t < Tn; ++t) {
    float pv = pbuf[t & 7];
    int tp = t + 8;
    pbuf[t & 7] = (tp < Tn) ? preb[(size_t)tp * 40] : 0.f;   // prefetch 8 ahead

    // z' = pv + sum_j wh[j]*hb[j]   (tree for short dependence)
    float m1 = wh[2] * hb[2];
    float m2 = wh[4] * hb[4];
    float m3 = wh[6] * hb[6];
    float m4 = wh[8] * hb[8];
    float s0 = fmaf(wh[0], hb[0], pv);
    float s1 = fmaf(wh[1], hb[1], m1);
    float s2 = fmaf(wh[3], hb[3], m2);
    float s3 = fmaf(wh[5], hb[5], m3);
    float s4 = fmaf(wh[7], hb[7], m4);
    s0 = fmaf(wh[9], hb[9], s0);
    float zs = (s0 + s1) + (s2 + (s3 + s4));

    float e = __builtin_amdgcn_exp2f(zs);
    float r = __builtin_amdgcn_rcpf(1.f + e);
    float gate = fmaf(ag, r, bgc);       // f/i/o: sigma(z); u: tanh(z)

    // gather i,u,o gates into lanes 0..9
    float iv = __int_as_float(__builtin_amdgcn_ds_bpermute(a1, __float_as_int(gate)));
    float uv = __int_as_float(__builtin_amdgcn_ds_bpermute(a2, __float_as_int(gate)));
    float ov = __int_as_float(__builtin_amdgcn_ds_bpermute(a3, __float_as_int(gate)));

    float iu = iv * uv;
    c = fmaf(c, gate, iu);               // lanes 0..9: c = c*f + i*u
    float zc = (2.f * NL2E) * c;
    float e2 = __builtin_amdgcn_exp2f(zc);
    float r2 = __builtin_amdgcn_rcpf(1.f + e2);
    float th = fmaf(2.f, r2, -1.f);      // tanh(c)
    h = ov * th;

    if (l < 10) outb[(size_t)o * Tn + t] = h;

    // broadcast h[0..9] to all lanes as wave-uniform (SGPR) values
#pragma unroll
    for (int j = 0; j < 10; ++j)
      hb[j] = __int_as_float(__builtin_amdgcn_readlane(__float_as_int(h), j));
  }
  if (l < 10) cTp[o] = c;
}

extern "C" void kernel_launch(void* const* d_in, const int* in_sizes, int n_in,
                              void* d_out, int out_size, void* d_ws, size_t ws_size,
                              hipStream_t stream) {
  const float* x      = (const float*)d_in[0];
  const float* y      = (const float*)d_in[1];
  const float* Wf     = (const float*)d_in[2];
  const float* bf     = (const float*)d_in[3];
  const float* Wi     = (const float*)d_in[4];
  const float* bi     = (const float*)d_in[5];
  const float* Wu     = (const float*)d_in[6];
  const float* bu     = (const float*)d_in[7];
  const float* Wo     = (const float*)d_in[8];
  const float* bo     = (const float*)d_in[9];
  const float* b_init = (const float*)d_in[11];
  float* out = (float*)d_out;
  float* pre = (float*)d_ws;   // needs B*T*40*4 = 26.2 MB

  dim3 g1(Tn / 256, Bn);
  pclstm_pre<<<g1, 256, 0, stream>>>(x, y, Wf, Wi, Wu, Wo, bf, bi, bu, bo, pre);
  pclstm_scan<<<Bn, 64, 0, stream>>>(pre, Wf, Wi, Wu, Wo, b_init, out);
}

// Round 2
// 1763.911 us; speedup vs baseline: 1.3698x; 1.3698x over previous
//
#include <hip/hip_runtime.h>

#define Bn 20
#define Cn 395
#define Hn 10
#define Tn 8192
#define GIN 800   // 2*C + H
#define NL2E (-1.4426950408889634f)

// ---------------- Phase 1: raw pre[b][t][o*4+g] = x.Wx + y_prev.Wy (bias folded into scan) ----
__global__ __launch_bounds__(128) void pclstm_pre(
    const float* __restrict__ x, const float* __restrict__ y,
    const float* __restrict__ Wf, const float* __restrict__ Wi,
    const float* __restrict__ Wu, const float* __restrict__ Wo,
    float* __restrict__ pre)
{
  __shared__ float wl[80 * 80];            // [c_local][80]: 40 Wx(q) then 40 Wy(q), q=g*10+h
  const int tid = threadIdx.x;
  const int b = blockIdx.y;
  const int t0 = blockIdx.x * 256 + tid;   // grid.x = Tn/256; each thread does t0 and t0+128
  const int t1 = t0 + 128;
  const int ty0 = (t0 > 0) ? t0 - 1 : 0;
  const float ym0 = (t0 > 0) ? 1.f : 0.f;

  const float* Wg[4] = {Wf, Wi, Wu, Wo};
  const float* xb = x + (size_t)b * Cn * Tn;
  const float* yb = y + (size_t)b * Cn * Tn;

  float acc0[40], acc1[40];
#pragma unroll
  for (int q = 0; q < 40; ++q) { acc0[q] = 0.f; acc1[q] = 0.f; }

  // x/y register ring buffers, prefetch depth 4 (c-iterations)
  float xr0[4], yr0[4], xr1[4], yr1[4];
#pragma unroll
  for (int d = 0; d < 4; ++d) {
    xr0[d] = xb[(size_t)d * Tn + t0];
    yr0[d] = ym0 * yb[(size_t)d * Tn + ty0];
    xr1[d] = xb[(size_t)d * Tn + t1];
    yr1[d] = yb[(size_t)d * Tn + t1 - 1];
  }

  for (int chunk = 0; chunk < 5; ++chunk) {
    const int c0 = chunk * 80;             // 5 chunks of 80 (zero-padded past 395)
    __syncthreads();
    for (int idx = tid; idx < 6400; idx += 128) {
      int cl = idx / 80;
      int q  = idx - cl * 80;
      int c  = c0 + cl;
      float v = 0.f;
      if (c < Cn) {
        int qq = (q < 40) ? q : q - 40;
        int g  = qq / 10;
        int h  = qq - g * 10;
        int col = (q < 40) ? c : (Cn + Hn + c);
        v = Wg[g][h * GIN + col];
      }
      wl[idx] = v;
    }
    __syncthreads();
#pragma unroll 4
    for (int cl = 0; cl < 80; ++cl) {
      const int slot = cl & 3;             // c0 multiple of 4 -> static under unroll 4
      float xv0 = xr0[slot], yv0 = yr0[slot];
      float xv1 = xr1[slot], yv1 = yr1[slot];
      int cp = c0 + cl + 4;
      cp = (cp < Cn) ? cp : (Cn - 1);      // clamp (padded weights are zero anyway)
      xr0[slot] = xb[(size_t)cp * Tn + t0];
      yr0[slot] = ym0 * yb[(size_t)cp * Tn + ty0];
      xr1[slot] = xb[(size_t)cp * Tn + t1];
      yr1[slot] = yb[(size_t)cp * Tn + t1 - 1];

      const float4* wrow = reinterpret_cast<const float4*>(&wl[cl * 80]);
#pragma unroll
      for (int k = 0; k < 10; ++k) {
        float4 wx = wrow[k];
        float4 wy = wrow[k + 10];
        acc0[4*k+0] = fmaf(xv0, wx.x, acc0[4*k+0]);
        acc0[4*k+1] = fmaf(xv0, wx.y, acc0[4*k+1]);
        acc0[4*k+2] = fmaf(xv0, wx.z, acc0[4*k+2]);
        acc0[4*k+3] = fmaf(xv0, wx.w, acc0[4*k+3]);
        acc0[4*k+0] = fmaf(yv0, wy.x, acc0[4*k+0]);
        acc0[4*k+1] = fmaf(yv0, wy.y, acc0[4*k+1]);
        acc0[4*k+2] = fmaf(yv0, wy.z, acc0[4*k+2]);
        acc0[4*k+3] = fmaf(yv0, wy.w, acc0[4*k+3]);
        acc1[4*k+0] = fmaf(xv1, wx.x, acc1[4*k+0]);
        acc1[4*k+1] = fmaf(xv1, wx.y, acc1[4*k+1]);
        acc1[4*k+2] = fmaf(xv1, wx.z, acc1[4*k+2]);
        acc1[4*k+3] = fmaf(xv1, wx.w, acc1[4*k+3]);
        acc1[4*k+0] = fmaf(yv1, wy.x, acc1[4*k+0]);
        acc1[4*k+1] = fmaf(yv1, wy.y, acc1[4*k+1]);
        acc1[4*k+2] = fmaf(yv1, wy.z, acc1[4*k+2]);
        acc1[4*k+3] = fmaf(yv1, wy.w, acc1[4*k+3]);
      }
    }
  }
  // store raw, reordered to [t][h*4+g] for the quad-based scan
  float* d0 = pre + ((size_t)b * Tn + t0) * 40;
  float* d1 = pre + ((size_t)b * Tn + t1) * 40;
#pragma unroll
  for (int q = 0; q < 40; ++q) {
    int g = q / 10;
    int h = q - g * 10;
    d0[h * 4 + g] = acc0[q];
    d1[h * 4 + g] = acc1[q];
  }
}

// ---------------- Phase 2: sequential scan, quad-per-output, DPP gate exchange ----------------
// lane l = o*4+g (l<40). All 4 lanes of quad o redundantly hold c[o], h[o].
#define QP(v, ctrl) __int_as_float(__builtin_amdgcn_update_dpp( \
    0, __float_as_int(v), (ctrl), 0xf, 0xf, true))

__global__ __launch_bounds__(64) void pclstm_scan(
    const float* __restrict__ pre,
    const float* __restrict__ Wf, const float* __restrict__ Wi,
    const float* __restrict__ Wu, const float* __restrict__ Wo,
    const float* __restrict__ bfp, const float* __restrict__ bip,
    const float* __restrict__ bup, const float* __restrict__ bop,
    const float* __restrict__ b_init,
    float* __restrict__ out)
{
  const int b = blockIdx.x;
  const int l = threadIdx.x;
  const int lc = (l < 40) ? l : 39;
  const int o = lc >> 2;
  const int g = lc & 3;

  const float* W  = (g == 0) ? Wf : (g == 1) ? Wi : (g == 2) ? Wu : Wo;
  const float* bp = (g == 0) ? bfp : (g == 1) ? bip : (g == 2) ? bup : bop;
  const float sg  = (g == 2) ? 2.f * NL2E : NL2E;   // -k_g*log2e folded into wh and pv
  const float ag  = (g == 2) ? 2.f : 1.f;           // gate = ag*sigm + bgc
  const float bgc = (g == 2) ? -1.f : 0.f;

  float wh[10];
#pragma unroll
  for (int j = 0; j < 10; ++j) wh[j] = W[o * GIN + Cn + j] * sg;
  const float sgb = sg * bp[o];

  const float* preb = pre + (size_t)b * Tn * 40 + lc;
  float c = b_init[o];
  float h = 0.f;
  float hb[10];
#pragma unroll
  for (int j = 0; j < 10; ++j) hb[j] = 0.f;

  float pbuf[8];
#pragma unroll
  for (int k = 0; k < 8; ++k) pbuf[k] = preb[(size_t)k * 40];

  const bool sl = (l < 40) && (g == 3);
  float* outb = out + (size_t)b * Hn * Tn;
  float hs[4];

#pragma unroll 8
  for (int t = 0; t < Tn; ++t) {
    float pv = pbuf[t & 7];
    int tp = t + 8;
    tp = (tp < Tn) ? tp : (Tn - 1);
    pbuf[t & 7] = preb[(size_t)tp * 40];              // prefetch 8 ahead

    float pvs = fmaf(sg, pv, sgb);                    // scale+bias, off critical path

    // z' = pvs + sum_j wh[j]*hb[j]   (balanced tree; hb are SGPR broadcasts)
    float m1 = wh[2] * hb[2];
    float m2 = wh[4] * hb[4];
    float m3 = wh[6] * hb[6];
    float m4 = wh[8] * hb[8];
    float s0 = fmaf(wh[0], hb[0], pvs);
    float s1 = fmaf(wh[1], hb[1], m1);
    float s2 = fmaf(wh[3], hb[3], m2);
    float s3 = fmaf(wh[5], hb[5], m3);
    float s4 = fmaf(wh[7], hb[7], m4);
    s0 = fmaf(wh[9], hb[9], s0);
    float zs = (s0 + s1) + (s2 + (s3 + s4));

    float e = __builtin_amdgcn_exp2f(zs);
    float r = __builtin_amdgcn_rcpf(1.f + e);
    float gate = fmaf(ag, r, bgc);                    // f/i/o: sigma; u: tanh

    // quad_perm broadcasts: gates of output o live in lanes 4o..4o+3
    float fv = QP(gate, 0x00);
    float iv = QP(gate, 0x55);
    float uv = QP(gate, 0xAA);
    float ov = QP(gate, 0xFF);

    c = fmaf(c, fv, iv * uv);
    float zc = (2.f * NL2E) * c;
    float e2 = __builtin_amdgcn_exp2f(zc);
    float r2 = __builtin_amdgcn_rcpf(1.f + e2);
    float th = fmaf(2.f, r2, -1.f);                   // tanh(c)
    h = ov * th;

    hs[t & 3] = h;
    if (((t & 3) == 3) && sl) {
      float4 v4; v4.x = hs[0]; v4.y = hs[1]; v4.z = hs[2]; v4.w = hs[3];
      *reinterpret_cast<float4*>(outb + (size_t)o * Tn + t - 3) = v4;
    }

    // broadcast h[0..9] (lane 4j) to all lanes as wave-uniform values
#pragma unroll
    for (int j = 0; j < 10; ++j)
      hb[j] = __int_as_float(__builtin_amdgcn_readlane(__float_as_int(h), 4 * j));
  }
  if ((l < 40) && (g == 0)) out[(size_t)Bn * Hn * Tn + b * Hn + o] = c;
}

extern "C" void kernel_launch(void* const* d_in, const int* in_sizes, int n_in,
                              void* d_out, int out_size, void* d_ws, size_t ws_size,
                              hipStream_t stream) {
  const float* x      = (const float*)d_in[0];
  const float* y      = (const float*)d_in[1];
  const float* Wf     = (const float*)d_in[2];
  const float* bf     = (const float*)d_in[3];
  const float* Wi     = (const float*)d_in[4];
  const float* bi     = (const float*)d_in[5];
  const float* Wu     = (const float*)d_in[6];
  const float* bu     = (const float*)d_in[7];
  const float* Wo     = (const float*)d_in[8];
  const float* bo     = (const float*)d_in[9];
  const float* b_init = (const float*)d_in[11];
  float* out = (float*)d_out;
  float* pre = (float*)d_ws;   // B*T*40*4 = 26.2 MB

  dim3 g1(Tn / 256, Bn);
  pclstm_pre<<<g1, 128, 0, stream>>>(x, y, Wf, Wi, Wu, Wo, pre);
  pclstm_scan<<<Bn, 64, 0, stream>>>(pre, Wf, Wi, Wu, Wo, bf, bi, bu, bo, b_init, out);
}

// Round 3
// 1492.266 us; speedup vs baseline: 1.6192x; 1.1820x over previous
//
#include <hip/hip_runtime.h>

#define Bn 20
#define Cn 395
#define Hn 10
#define Tn 8192
#define TP (Tn + 8)          // padded timesteps in the pre buffer (scan prefetch slack)
#define GIN 800              // 2*C + H
#define CP 400               // padded C so the c-loop is an exact multiple of 8
#define NL2E (-1.4426950408889634f)

// ---------------- Phase 0: build scaled, scan-ordered weight table ----------------------------
// wt[c][q]      = Wg[h][c]        * s_g   (q = h*4+g, x part)
// wt[c][40+q]   = Wg[h][C+H+c]    * s_g   (y part);  rows c>=395 are zero padding.
__global__ __launch_bounds__(256) void pclstm_wt(
    const float* __restrict__ Wf, const float* __restrict__ Wi,
    const float* __restrict__ Wu, const float* __restrict__ Wo,
    float* __restrict__ wt)
{
  int i = blockIdx.x * 256 + threadIdx.x;        // over CP*80
  if (i >= CP * 80) return;
  int c = i / 80;
  int q = i - c * 80;
  float v = 0.f;
  if (c < Cn) {
    int qq = (q < 40) ? q : q - 40;
    int h = qq >> 2;
    int g = qq & 3;
    const float* W = (g == 0) ? Wf : (g == 1) ? Wi : (g == 2) ? Wu : Wo;
    float s = (g == 2) ? 2.f * NL2E : NL2E;
    int col = (q < 40) ? c : (Cn + Hn + c);
    v = W[h * GIN + col] * s;
  }
  wt[i] = v;
}

// ---------------- Phase 1: pre[b][t][q] = (x.Wx + y_prev.Wy) * s_g  (bias added in scan) ------
// Weights read via wave-uniform addresses -> scalar (s_load) broadcasts; no LDS, no barriers.
__global__ __launch_bounds__(256) void pclstm_pre(
    const float* __restrict__ x, const float* __restrict__ y,
    const float* __restrict__ wt, float* __restrict__ pre)
{
  const int tid = threadIdx.x;
  const int b = blockIdx.y;
  const int t = blockIdx.x * 256 + tid;

  const float* xb = x + (size_t)b * Cn * Tn + t;
  const float* yb = y + (size_t)b * Cn * Tn + ((t > 0) ? t - 1 : 0);
  const float ym = (t > 0) ? 1.f : 0.f;

  float acc[40];
#pragma unroll
  for (int q = 0; q < 40; ++q) acc[q] = 0.f;

  // 8-deep register ring prefetch of x / y_prev
  float xr[8], yr[8];
#pragma unroll
  for (int d = 0; d < 8; ++d) {
    xr[d] = xb[(size_t)d * Tn];
    yr[d] = ym * yb[(size_t)d * Tn];
  }

#pragma unroll 8
  for (int c = 0; c < CP; ++c) {                 // CP=400 = 50*8, no remainder
    const int slot = c & 7;                      // static under unroll 8
    float xv = xr[slot];
    float yv = yr[slot];
    int cp = c + 8;
    cp = (cp < Cn) ? cp : (Cn - 1);              // uniform clamp (pad rows multiply by 0)
    xr[slot] = xb[(size_t)cp * Tn];
    yr[slot] = ym * yb[(size_t)cp * Tn];

    const float4* wr4 = reinterpret_cast<const float4*>(wt + c * 80);  // uniform address
#pragma unroll
    for (int k = 0; k < 10; ++k) {
      float4 wx = wr4[k];
      float4 wy = wr4[k + 10];
      acc[4*k+0] = fmaf(xv, wx.x, acc[4*k+0]);
      acc[4*k+1] = fmaf(xv, wx.y, acc[4*k+1]);
      acc[4*k+2] = fmaf(xv, wx.z, acc[4*k+2]);
      acc[4*k+3] = fmaf(xv, wx.w, acc[4*k+3]);
      acc[4*k+0] = fmaf(yv, wy.x, acc[4*k+0]);
      acc[4*k+1] = fmaf(yv, wy.y, acc[4*k+1]);
      acc[4*k+2] = fmaf(yv, wy.z, acc[4*k+2]);
      acc[4*k+3] = fmaf(yv, wy.w, acc[4*k+3]);
    }
  }

  float4* dst = reinterpret_cast<float4*>(pre + ((size_t)b * TP + t) * 40);
#pragma unroll
  for (int k = 0; k < 10; ++k) {
    float4 v4;
    v4.x = acc[4*k+0]; v4.y = acc[4*k+1]; v4.z = acc[4*k+2]; v4.w = acc[4*k+3];
    dst[k] = v4;
  }
}

// ---------------- Phase 2: sequential scan, quad-per-output, DPP gate exchange ----------------
// lane l = o*4+g (l<40). All 4 lanes of quad o redundantly hold c[o], h[o].
#define QP(v, ctrl) __int_as_float(__builtin_amdgcn_update_dpp( \
    0, __float_as_int(v), (ctrl), 0xf, 0xf, true))

__global__ __launch_bounds__(64) void pclstm_scan(
    const float* __restrict__ pre,
    const float* __restrict__ Wf, const float* __restrict__ Wi,
    const float* __restrict__ Wu, const float* __restrict__ Wo,
    const float* __restrict__ bfp, const float* __restrict__ bip,
    const float* __restrict__ bup, const float* __restrict__ bop,
    const float* __restrict__ b_init,
    float* __restrict__ out)
{
  const int b = blockIdx.x;
  const int l = threadIdx.x;
  const int lc = (l < 40) ? l : 39;
  const int o = lc >> 2;
  const int g = lc & 3;

  const float* W  = (g == 0) ? Wf : (g == 1) ? Wi : (g == 2) ? Wu : Wo;
  const float* bp = (g == 0) ? bfp : (g == 1) ? bip : (g == 2) ? bup : bop;
  const float sg  = (g == 2) ? 2.f * NL2E : NL2E;   // -k_g*log2e folded into wh and pre
  const float ag  = (g == 2) ? 2.f : 1.f;           // gate = ag*sigm + bgc
  const float bgc = (g == 2) ? -1.f : 0.f;

  float wh[10];
#pragma unroll
  for (int j = 0; j < 10; ++j) wh[j] = W[o * GIN + Cn + j] * sg;
  const float sgb = sg * bp[o];

  const float* preb = pre + (size_t)b * TP * 40 + lc;
  float c = b_init[o];
  float h = 0.f;
  float hb[10];
#pragma unroll
  for (int j = 0; j < 10; ++j) hb[j] = 0.f;

  float pbuf[8];
#pragma unroll
  for (int k = 0; k < 8; ++k) pbuf[k] = preb[(size_t)k * 40];

  const bool sl = (l < 40) && (g == 3);
  float* outb = out + (size_t)b * Hn * Tn;
  float hs[4];

#pragma unroll 8
  for (int t = 0; t < Tn; ++t) {
    float pv = pbuf[t & 7];
    pbuf[t & 7] = preb[(size_t)(t + 8) * 40];         // linear prefetch into pad region

    float pvs = pv + sgb;                             // pre already scaled

    // z' = pvs + sum_j wh[j]*hb[j]   (balanced tree; hb are SGPR broadcasts)
    float m1 = wh[2] * hb[2];
    float m2 = wh[4] * hb[4];
    float m3 = wh[6] * hb[6];
    float m4 = wh[8] * hb[8];
    float s0 = fmaf(wh[0], hb[0], pvs);
    float s1 = fmaf(wh[1], hb[1], m1);
    float s2 = fmaf(wh[3], hb[3], m2);
    float s3 = fmaf(wh[5], hb[5], m3);
    float s4 = fmaf(wh[7], hb[7], m4);
    s0 = fmaf(wh[9], hb[9], s0);
    float zs = (s0 + s1) + (s2 + (s3 + s4));

    float e = __builtin_amdgcn_exp2f(zs);
    float r = __builtin_amdgcn_rcpf(1.f + e);
    float gate = fmaf(ag, r, bgc);                    // f/i/o: sigma; u: tanh

    // quad_perm broadcasts: gates of output o live in lanes 4o..4o+3
    float fv = QP(gate, 0x00);
    float iv = QP(gate, 0x55);
    float uv = QP(gate, 0xAA);
    float ov = QP(gate, 0xFF);

    c = fmaf(c, fv, iv * uv);
    float zc = (2.f * NL2E) * c;
    float e2 = __builtin_amdgcn_exp2f(zc);
    float r2 = __builtin_amdgcn_rcpf(1.f + e2);
    float th = fmaf(2.f, r2, -1.f);                   // tanh(c)
    h = ov * th;

    hs[t & 3] = h;
    if (((t & 3) == 3) && sl) {
      float4 v4; v4.x = hs[0]; v4.y = hs[1]; v4.z = hs[2]; v4.w = hs[3];
      *reinterpret_cast<float4*>(outb + (size_t)o * Tn + t - 3) = v4;
    }

    // broadcast h[0..9] (lane 4j) to all lanes as wave-uniform values
#pragma unroll
    for (int j = 0; j < 10; ++j)
      hb[j] = __int_as_float(__builtin_amdgcn_readlane(__float_as_int(h), 4 * j));
  }
  if ((l < 40) && (g == 0)) out[(size_t)Bn * Hn * Tn + b * Hn + o] = c;
}

extern "C" void kernel_launch(void* const* d_in, const int* in_sizes, int n_in,
                              void* d_out, int out_size, void* d_ws, size_t ws_size,
                              hipStream_t stream) {
  const float* x      = (const float*)d_in[0];
  const float* y      = (const float*)d_in[1];
  const float* Wf     = (const float*)d_in[2];
  const float* bf     = (const float*)d_in[3];
  const float* Wi     = (const float*)d_in[4];
  const float* bi     = (const float*)d_in[5];
  const float* Wu     = (const float*)d_in[6];
  const float* bu     = (const float*)d_in[7];
  const float* Wo     = (const float*)d_in[8];
  const float* bo     = (const float*)d_in[9];
  const float* b_init = (const float*)d_in[11];
  float* out = (float*)d_out;

  float* wt  = (float*)d_ws;                      // CP*80*4 = 128 KB
  float* pre = (float*)((char*)d_ws + 131072);    // Bn*TP*40*4 = 26.24 MB

  pclstm_wt<<<(CP * 80 + 255) / 256, 256, 0, stream>>>(Wf, Wi, Wu, Wo, wt);
  dim3 g1(Tn / 256, Bn);
  pclstm_pre<<<g1, 256, 0, stream>>>(x, y, wt, pre);
  pclstm_scan<<<Bn, 64, 0, stream>>>(pre, Wf, Wi, Wu, Wo, bf, bi, bu, bo, b_init, out);
}